// Round 16
// baseline (165.542 us; speedup 1.0000x reference)
//
#include <hip/hip_runtime.h>
#include <math.h>

#define DD 4096
#define EE 64
#define TAU 1e-4f
#define NEG_SENTINEL -1.0e30f
#define MAXFIX 4096
#define NREP 2  // R16: measurement round — K-sweep repeated to surface gemm in rocprof top-5

typedef __attribute__((ext_vector_type(8))) short short8v;
typedef __attribute__((ext_vector_type(4))) float f32x4;

union BF8 { uint4 u; short8v s; };

__device__ __forceinline__ unsigned asu(float f) {
  union { float f; unsigned u; } v; v.f = f; return v.u;
}
__device__ __forceinline__ float asf(unsigned u) {
  union { unsigned u; float f; } v; v.u = u; return v.f;
}
__device__ __forceinline__ unsigned rne_hi(float x) {  // bf16 bits<<16
  unsigned u = asu(x);
  return (u + 0x7fffu + ((u >> 16) & 1u)) & 0xffff0000u;
}
// Split 8 f32 into hi/lo bf16 (RNE both): x = hi + lo + O(2^-17 |x|).
__device__ __forceinline__ void split8(const float x[8], uint4& hi, uint4& lo) {
  unsigned h[8], l[8];
#pragma unroll
  for (int j = 0; j < 8; j++) {
    h[j] = rne_hi(x[j]);
    l[j] = rne_hi(x[j] - asf(h[j]));
  }
  hi = make_uint4((h[0] >> 16) | h[1], (h[2] >> 16) | h[3],
                  (h[4] >> 16) | h[5], (h[6] >> 16) | h[7]);
  lo = make_uint4((l[0] >> 16) | l[1], (l[2] >> 16) | l[3],
                  (l[4] >> 16) | l[5], (l[6] >> 16) | l[7]);
}
// global -> LDS direct copy, 16B/lane; LDS dest wave-uniform (HW adds l*16).
__device__ __forceinline__ void gload16(const void* g, void* l) {
  __builtin_amdgcn_global_load_lds(
      (const __attribute__((address_space(1))) uint32_t*)(uintptr_t)g,
      (__attribute__((address_space(3))) uint32_t*)(uint32_t)(uintptr_t)l, 16,
      0, 0);
}

// ---------------------------------------------------------------------------
// Kernel 0: pre-split gate_w into bf16 hi/lo in the gemm's exact STAGED
// layout (identical to R14).
// ---------------------------------------------------------------------------
__global__ __launch_bounds__(256) void presplit_b(const float* __restrict__ gw,
                                                  char* __restrict__ bglob) {
  const int t = blockIdx.x * 256 + threadIdx.x;  // 64 e x 512 octets
  const int e = t >> 9;
  const int o = t & 511;
  const int slice = o >> 6;   // 64 octets per 512-k slice
  const int ow = o & 63;
  const int step = ow >> 2;   // 4 octets per 32-k step
  const int oslot = ow & 3;
  const float* src = gw + e * DD + o * 8;
  float4 v0 = *(const float4*)src;
  float4 v1 = *(const float4*)(src + 4);
  float x[8] = {v0.x, v0.y, v0.z, v0.w, v1.x, v1.y, v1.z, v1.w};
  uint4 hi, lo;
  split8(x, hi, lo);
  char* dst = bglob + (size_t)slice * 131072 + step * 8192 + e * 64 +
              ((oslot ^ ((e >> 1) & 3)) << 4);
  *(uint4*)dst = hi;
  *(uint4*)(dst + 4096) = lo;
}

// ---------------------------------------------------------------------------
// Kernel 1 (R16 = R14 x NREP): byte-identical pipeline to R14, with the
// whole K-sweep (acc init -> staged loop -> write) executed NREP times.
// Sweep 2 recomputes identical values (deterministic, same output) — its
// only purpose is to make this dispatch ~175us so it surfaces ABOVE the
// harness's 155us poison fills in rocprof top-5, giving first-ever direct
// counters (MfmaUtil/VALUBusy/hbm_gbps/FETCH/bank-conflict) on the real
// kernel. Diagnosis round: dur_us intentionally sacrificed.
// ---------------------------------------------------------------------------
__global__ __launch_bounds__(256, 2) void gemm_mfma(
    const float* __restrict__ hidden, const char* __restrict__ bglob,
    float* __restrict__ part, int nrows) {
  __shared__ __align__(16) char smem[81920];  // 2 bufs x [A 32K | B 8K]

  const int lane = threadIdx.x & 63;
  const int wv = threadIdx.x >> 6;
  const int fr = lane & 15;
  const int fg = lane >> 4;  // 0..3
  const int m0 = blockIdx.x * 256;
  const int slice = blockIdx.y;  // ksplit = 8, kslice = 512
  const int k0 = slice * 512;

  const float* srcA[8];
#pragma unroll
  for (int i = 0; i < 8; i++) {
    const int rloc = 8 * i + (lane >> 3);
    const int s = (lane & 7) ^ (rloc & 7);
    srcA[i] = hidden + (size_t)(m0 + 64 * wv + rloc) * DD + k0 + s * 4;
  }
  const char* srcB = bglob + (size_t)slice * 131072 + wv * 2048 + lane * 16;

  auto stage = [&](int t) {
    const int buf = t & 1;
    char* ad = smem + buf * 40960 + wv * 8192;
    char* bd = smem + buf * 40960 + 32768 + wv * 2048;
#pragma unroll
    for (int i = 0; i < 8; i++) gload16(srcA[i] + t * 32, ad + i * 1024);
#pragma unroll
    for (int i = 0; i < 2; i++)
      gload16(srcB + t * 8192 + i * 1024, bd + i * 1024);
  };

  const int bslot = (fg ^ ((fr >> 1) & 3)) << 4;
  f32x4 zero4 = {0.f, 0.f, 0.f, 0.f};

  for (int rep = 0; rep < NREP; rep++) {
    f32x4 acc[4][4];
#pragma unroll
    for (int mt = 0; mt < 4; mt++)
#pragma unroll
      for (int nt = 0; nt < 4; nt++) acc[mt][nt] = zero4;

    stage(0);
    __syncthreads();

    for (int t = 0; t < 16; t++) {
      if (t + 1 < 16) stage(t + 1);
      const char* Ab = smem + (t & 1) * 40960 + wv * 8192;
      const char* Bb = smem + (t & 1) * 40960 + 32768;
      BF8 bh[4], bl[4];
#pragma unroll
      for (int nt = 0; nt < 4; nt++) {
        const int boff = (nt * 16 + fr) * 64 + bslot;
        bh[nt].u = *(const uint4*)(Bb + boff);
        bl[nt].u = *(const uint4*)(Bb + 4096 + boff);
      }
#pragma unroll
      for (int mt = 0; mt < 4; mt++) {
        const int arow = (mt * 16 + fr) * 128;
        float4 a0 =
            *(const float4*)(Ab + arow + (((2 * fg + 0) ^ (fr & 7)) << 4));
        float4 a1 =
            *(const float4*)(Ab + arow + (((2 * fg + 1) ^ (fr & 7)) << 4));
        float xa[8] = {a0.x, a0.y, a0.z, a0.w, a1.x, a1.y, a1.z, a1.w};
        BF8 ah, al;
        split8(xa, ah.u, al.u);
#pragma unroll
        for (int nt = 0; nt < 4; nt++)
          acc[mt][nt] = __builtin_amdgcn_mfma_f32_16x16x32_bf16(
              ah.s, bh[nt].s, acc[mt][nt], 0, 0, 0);
#pragma unroll
        for (int nt = 0; nt < 4; nt++)
          acc[mt][nt] = __builtin_amdgcn_mfma_f32_16x16x32_bf16(
              ah.s, bl[nt].s, acc[mt][nt], 0, 0, 0);
#pragma unroll
        for (int nt = 0; nt < 4; nt++)
          acc[mt][nt] = __builtin_amdgcn_mfma_f32_16x16x32_bf16(
              al.s, bh[nt].s, acc[mt][nt], 0, 0, 0);
      }
      __syncthreads();
    }

    // partial logits part[slice][row][e]; C/D row=fg*4+j, col=fr
    float* dst = part + (size_t)slice * nrows * EE;
#pragma unroll
    for (int mt = 0; mt < 4; mt++)
#pragma unroll
      for (int j = 0; j < 4; j++) {
        const int r = m0 + 64 * wv + mt * 16 + fg * 4 + j;
#pragma unroll
        for (int nt = 0; nt < 4; nt++)
          dst[(size_t)r * EE + nt * 16 + fr] = acc[mt][nt][j];
      }
    __syncthreads();  // all writes/reads done before rep 2 restages buf0
  }
}

// ---------------------------------------------------------------------------
// Kernel 2: reduce partials, sqrt(softplus), top-8 (lax.top_k tie-break),
// renormalize, scatter. Flags rows with margin < TAU for exact recompute.
// ---------------------------------------------------------------------------
__global__ __launch_bounds__(256) void topk_kernel(
    const float* __restrict__ part, const float* __restrict__ bias,
    float* __restrict__ out, int nrows, int ksplit, int* __restrict__ counter,
    int* __restrict__ list) {
  const int lane = threadIdx.x & 63;
  const int row = blockIdx.x * 4 + (threadIdx.x >> 6);

  float logit = 0.0f;
  for (int s = 0; s < ksplit; s++)
    logit += part[(size_t)s * nrows * EE + (size_t)row * EE + lane];

  float sp = (logit > 0.0f) ? (logit + log1pf(expf(-logit)))
                            : log1pf(expf(logit));
  float score = sqrtf(sp);
  float sel = score + bias[lane];

  float denom = 0.0f, v8 = 0.0f;
  bool chosen = false;
#pragma unroll
  for (int t = 0; t < 8; t++) {
    float v = sel;
    int idx = lane;
#pragma unroll
    for (int m = 1; m < 64; m <<= 1) {
      float ov = __shfl_xor(v, m, 64);
      int oi = __shfl_xor(idx, m, 64);
      if (ov > v || (ov == v && oi < idx)) { v = ov; idx = oi; }
    }
    float wscore = __shfl(score, idx, 64);
    denom += wscore;
    v8 = v;
    if (lane == idx) { chosen = true; sel = NEG_SENTINEL; }
  }
  float v9 = sel;
#pragma unroll
  for (int m = 1; m < 64; m <<= 1) v9 = fmaxf(v9, __shfl_xor(v9, m, 64));
  if (lane == 0 && (v8 - v9) < TAU) {
    int ix = atomicAdd(counter, 1);
    if (ix < MAXFIX) list[ix] = row;
  }

  denom = fmaxf(denom, 1e-12f);
  out[(size_t)row * EE + lane] = chosen ? (score / denom) : 0.0f;
  out[(size_t)nrows * EE + (size_t)row * EE + lane] = chosen ? 1.0f : 0.0f;
}

// ---------------------------------------------------------------------------
// Kernel 3a: exact-f32 partial dots for flagged rows, k-split 16 ways.
// ---------------------------------------------------------------------------
__global__ __launch_bounds__(256) void fixup_partial(
    const float* __restrict__ hidden, const float* __restrict__ gate_w,
    const int* __restrict__ counter, const int* __restrict__ list,
    float* __restrict__ part2) {
  __shared__ float red[EE][4];
  int cnt = *counter;
  if (cnt > MAXFIX) cnt = MAXFIX;
  const int total = cnt * 16;
  const int e = threadIdx.x & 63;
  const int q = threadIdx.x >> 6;
  for (int w = blockIdx.x; w < total; w += gridDim.x) {
    const int i = w >> 4;
    const int c = w & 15;
    const int row = list[i];
    const int kb = c * 256 + q * 64;
    const float* hp = hidden + (size_t)row * DD + kb;
    const float* wp = gate_w + (size_t)e * DD + kb;
    float s = 0.f;
#pragma unroll
    for (int k = 0; k < 64; k += 4) {
      float4 aa = *(const float4*)(hp + k);
      float4 bb = *(const float4*)(wp + k);
      s = fmaf(aa.w, bb.w, fmaf(aa.z, bb.z, fmaf(aa.y, bb.y, fmaf(aa.x, bb.x, s))));
    }
    red[e][q] = s;
    __syncthreads();
    if (threadIdx.x < EE)
      part2[(size_t)i * 1024 + threadIdx.x * 16 + c] =
          (red[threadIdx.x][0] + red[threadIdx.x][1]) +
          (red[threadIdx.x][2] + red[threadIdx.x][3]);
    __syncthreads();
  }
}

// ---------------------------------------------------------------------------
// Kernel 3b: sum the 16 chunks in fixed order, redo top-8 exactly, rewrite.
// ---------------------------------------------------------------------------
__global__ __launch_bounds__(256) void fixup_apply(
    const float* __restrict__ part2, const float* __restrict__ bias,
    const int* __restrict__ counter, const int* __restrict__ list,
    float* __restrict__ out, int nrows) {
  int cnt = *counter;
  if (cnt > MAXFIX) cnt = MAXFIX;
  const int lane = threadIdx.x & 63;
  const int wv = threadIdx.x >> 6;
  for (int i0 = blockIdx.x * 4; i0 < cnt; i0 += gridDim.x * 4) {
    const int i = i0 + wv;
    if (i >= cnt) continue;
    const int row = list[i];
    const float* pp = part2 + (size_t)i * 1024 + lane * 16;
    float logit = 0.f;
#pragma unroll
    for (int c = 0; c < 16; c++) logit += pp[c];
    float sp = (logit > 0.0f) ? (logit + log1pf(expf(-logit)))
                              : log1pf(expf(logit));
    float score = sqrtf(sp);
    float sel = score + bias[lane];
    float denom = 0.0f;
    bool chosen = false;
#pragma unroll
    for (int k = 0; k < 8; k++) {
      float v = sel;
      int idx = lane;
#pragma unroll
      for (int m = 1; m < 64; m <<= 1) {
        float ov = __shfl_xor(v, m, 64);
        int oi = __shfl_xor(idx, m, 64);
        if (ov > v || (ov == v && oi < idx)) { v = ov; idx = oi; }
      }
      float wscore = __shfl(score, idx, 64);
      denom += wscore;
      if (lane == idx) { chosen = true; sel = NEG_SENTINEL; }
    }
    denom = fmaxf(denom, 1e-12f);
    out[(size_t)row * EE + lane] = chosen ? (score / denom) : 0.0f;
    out[(size_t)nrows * EE + (size_t)row * EE + lane] = chosen ? 1.0f : 0.0f;
  }
}

// ---------------------------------------------------------------------------
extern "C" void kernel_launch(void* const* d_in, const int* in_sizes, int n_in,
                              void* d_out, int out_size, void* d_ws,
                              size_t ws_size, hipStream_t stream) {
  const float* hidden = (const float*)d_in[0];
  const float* gate_w = (const float*)d_in[1];
  const float* bias = (const float*)d_in[2];
  float* out = (float*)d_out;
  char* ws = (char*)d_ws;

  const int nrows = in_sizes[0] / DD;  // 16384

  // ws: bglob @0 (1MB) | part @2MB (32MB) | part2 @36MB (16MB) | tail ctr
  char* bglob = ws;
  float* part = (float*)(ws + (size_t)2 * 1024 * 1024);
  float* part2 = (float*)(ws + (size_t)36 * 1024 * 1024);
  size_t tail = (ws_size - 65536) & ~(size_t)255;
  int* counter = (int*)(ws + tail);
  int* list = counter + 1;

  hipMemsetAsync(counter, 0, sizeof(int), stream);
  presplit_b<<<dim3(128), dim3(256), 0, stream>>>(gate_w, bglob);
  gemm_mfma<<<dim3(nrows / 256, 8), dim3(256), 0, stream>>>(hidden, bglob,
                                                            part, nrows);
  topk_kernel<<<dim3(nrows / 4), dim3(256), 0, stream>>>(part, bias, out,
                                                         nrows, 8, counter,
                                                         list);
  fixup_partial<<<dim3(2048), dim3(256), 0, stream>>>(hidden, gate_w, counter,
                                                      list, part2);
  fixup_apply<<<dim3(512), dim3(256), 0, stream>>>(part2, bias, counter, list,
                                                   out, nrows);
}

// Round 17
// 113.018 us; speedup vs baseline: 1.4647x; 1.4647x over previous
//
#include <hip/hip_runtime.h>
#include <math.h>

#define DD 4096
#define EE 64
#define TAU 1e-4f
#define NEG_SENTINEL -1.0e30f
#define MAXFIX 4096

typedef __attribute__((ext_vector_type(8))) short short8v;
typedef __attribute__((ext_vector_type(4))) float f32x4;

union BF8 { uint4 u; short8v s; };

__device__ __forceinline__ unsigned asu(float f) {
  union { float f; unsigned u; } v; v.f = f; return v.u;
}
__device__ __forceinline__ float asf(unsigned u) {
  union { unsigned u; float f; } v; v.u = u; return v.f;
}
__device__ __forceinline__ unsigned rne_hi(float x) {  // bf16 bits<<16
  unsigned u = asu(x);
  return (u + 0x7fffu + ((u >> 16) & 1u)) & 0xffff0000u;
}
// Split 8 f32 into hi/lo bf16 (RNE both): x = hi + lo + O(2^-17 |x|).
__device__ __forceinline__ void split8(const float x[8], uint4& hi, uint4& lo) {
  unsigned h[8], l[8];
#pragma unroll
  for (int j = 0; j < 8; j++) {
    h[j] = rne_hi(x[j]);
    l[j] = rne_hi(x[j] - asf(h[j]));
  }
  hi = make_uint4((h[0] >> 16) | h[1], (h[2] >> 16) | h[3],
                  (h[4] >> 16) | h[5], (h[6] >> 16) | h[7]);
  lo = make_uint4((l[0] >> 16) | l[1], (l[2] >> 16) | l[3],
                  (l[4] >> 16) | l[5], (l[6] >> 16) | l[7]);
}
// global -> LDS direct copy, 16B/lane; LDS dest wave-uniform (HW adds l*16).
__device__ __forceinline__ void gload16(const void* g, void* l) {
  __builtin_amdgcn_global_load_lds(
      (const __attribute__((address_space(1))) uint32_t*)(uintptr_t)g,
      (__attribute__((address_space(3))) uint32_t*)(uint32_t)(uintptr_t)l, 16,
      0, 0);
}

// ---------------------------------------------------------------------------
// Kernel 0: pre-split gate_w into bf16 hi/lo in the gemm's exact STAGED
// layout (identical to R14): bglob[slice(512k)][step(32k)][hi|lo][e][slot];
// source k-octet o of expert e -> slot (o&3) ^ ((e>>1)&3).
// ---------------------------------------------------------------------------
__global__ __launch_bounds__(256) void presplit_b(const float* __restrict__ gw,
                                                  char* __restrict__ bglob) {
  const int t = blockIdx.x * 256 + threadIdx.x;  // 64 e x 512 octets
  const int e = t >> 9;
  const int o = t & 511;
  const int slice = o >> 6;   // 64 octets per 512-k slice
  const int ow = o & 63;
  const int step = ow >> 2;   // 4 octets per 32-k step
  const int oslot = ow & 3;
  const float* src = gw + e * DD + o * 8;
  float4 v0 = *(const float4*)src;
  float4 v1 = *(const float4*)(src + 4);
  float x[8] = {v0.x, v0.y, v0.z, v0.w, v1.x, v1.y, v1.z, v1.w};
  uint4 hi, lo;
  split8(x, hi, lo);
  char* dst = bglob + (size_t)slice * 131072 + step * 8192 + e * 64 +
              ((oslot ^ ((e >> 1) & 3)) << 4);
  *(uint4*)dst = hi;
  *(uint4*)(dst + 4096) = lo;
}

// ---------------------------------------------------------------------------
// Kernel 1 (R17): 4 INDEPENDENT BLOCKS/CU via B-single-buffer, 40KB LDS.
// BM=128 x 64 e x BK=32; 4 waves; wave = 32 rows (mt=2). ksplit=8 ->
// grid (128,8) = 1024 = exactly 4 blocks/CU resident (16 waves/CU).
// LDS 40KB: A ring 2x16KB @0 (f32, R12-proven source swizzle), B 8KB @32768
// (pre-split bf16 hi/lo, staged verbatim).
// Two-raw-barrier step (B write-after-read safe):
//   P1 vmcnt(0); s_barrier          [stage(t) landed everywhere]
//   P2 ds_read A frags + B frags    [into registers]
//   P3 lgkmcnt(0); s_barrier        [ALL waves' reads done -> B overwritable]
//   P4 stage B(t+1)->Bbuf, A(t+1)->ring[(t+1)&1]   (issue-only, flies)
//   P5 sched_barrier; split8 + 24 MFMA
// A-parity safety: A(t+1) write lands after P3 of step t, and reads of that
// buffer ended at step t-1's P3. Bytes: A 256MB + B 128MB = 384MB
// (port floor 62us); 4 indep blocks cover each other's P1 drains.
// ---------------------------------------------------------------------------
__global__ __launch_bounds__(256, 4) void gemm_mfma(
    const float* __restrict__ hidden, const char* __restrict__ bglob,
    float* __restrict__ part, int nrows) {
  __shared__ __align__(16) char smem[40960];  // A: 2x16K @0 | B: 8K @32768

  const int lane = threadIdx.x & 63;
  const int wv = threadIdx.x >> 6;
  const int fr = lane & 15;
  const int fg = lane >> 4;  // 0..3
  const int m0 = blockIdx.x * 128;
  const int slice = blockIdx.y;  // ksplit = 8, kslice = 512
  const int k0 = slice * 512;

  // A sources: wave wv stages rows 32wv..+31; instr i covers rows 8i..8i+7.
  // lane l -> r = 32wv+8i+(l>>3), source slot (l&7)^(r&7); phys slot l&7.
  const float* srcA[4];
#pragma unroll
  for (int i = 0; i < 4; i++) {
    const int rw = 8 * i + (lane >> 3);            // row within wave 0..31
    const int s = (lane & 7) ^ (rw & 7);
    srcA[i] = hidden + (size_t)(m0 + 32 * wv + rw) * DD + k0 + s * 4;
  }
  const char* srcB = bglob + (size_t)slice * 131072 + wv * 2048 + lane * 16;

  auto stageA = [&](int t) {
    char* ad = smem + (t & 1) * 16384 + wv * 4096;
#pragma unroll
    for (int i = 0; i < 4; i++) gload16(srcA[i] + t * 32, ad + i * 1024);
  };
  auto stageB = [&](int t) {
    char* bd = smem + 32768 + wv * 2048;
#pragma unroll
    for (int i = 0; i < 2; i++)
      gload16(srcB + t * 8192 + i * 1024, bd + i * 1024);
  };

  f32x4 zero4 = {0.f, 0.f, 0.f, 0.f};
  f32x4 acc[2][4];
#pragma unroll
  for (int mt = 0; mt < 2; mt++)
#pragma unroll
    for (int nt = 0; nt < 4; nt++) acc[mt][nt] = zero4;

  const int bslot = (fg ^ ((fr >> 1) & 3)) << 4;

  // prologue: stage(0) in flight; drained by t=0's P1
  stageB(0);
  stageA(0);

  for (int t = 0; t < 16; t++) {
    // P1: everything issued so far (= stage(t)) landed; all waves fenced
    asm volatile("s_waitcnt vmcnt(0)" ::: "memory");
    __builtin_amdgcn_s_barrier();
    asm volatile("" ::: "memory");

    // P2: read all fragments into registers
    const char* Ab = smem + (t & 1) * 16384;
    const char* Bb = smem + 32768;
    float4 a0[2], a1[2];
#pragma unroll
    for (int mt = 0; mt < 2; mt++) {
      const int arow = (32 * wv + mt * 16 + fr) * 128;
      a0[mt] = *(const float4*)(Ab + arow + (((2 * fg + 0) ^ (fr & 7)) << 4));
      a1[mt] = *(const float4*)(Ab + arow + (((2 * fg + 1) ^ (fr & 7)) << 4));
    }
    BF8 bh[4], bl[4];
#pragma unroll
    for (int nt = 0; nt < 4; nt++) {
      const int boff = (nt * 16 + fr) * 64 + bslot;
      bh[nt].u = *(const uint4*)(Bb + boff);
      bl[nt].u = *(const uint4*)(Bb + 4096 + boff);
    }

    // P3: my reads complete; all waves' reads complete -> B overwritable
    asm volatile("s_waitcnt lgkmcnt(0)" ::: "memory");
    __builtin_amdgcn_s_barrier();
    asm volatile("" ::: "memory");

    // P4: issue next-step stages (fly through P5 + other blocks' phases)
    if (t + 1 < 16) {
      stageB(t + 1);
      stageA(t + 1);
    }
    __builtin_amdgcn_sched_barrier(0);  // keep MFMAs below the issue

    // P5: split + 24 MFMAs (per-acc order hh->hl->lh, deterministic)
#pragma unroll
    for (int mt = 0; mt < 2; mt++) {
      float xa[8] = {a0[mt].x, a0[mt].y, a0[mt].z, a0[mt].w,
                     a1[mt].x, a1[mt].y, a1[mt].z, a1[mt].w};
      BF8 ah, al;
      split8(xa, ah.u, al.u);
#pragma unroll
      for (int nt = 0; nt < 4; nt++)
        acc[mt][nt] = __builtin_amdgcn_mfma_f32_16x16x32_bf16(
            ah.s, bh[nt].s, acc[mt][nt], 0, 0, 0);
#pragma unroll
      for (int nt = 0; nt < 4; nt++)
        acc[mt][nt] = __builtin_amdgcn_mfma_f32_16x16x32_bf16(
            ah.s, bl[nt].s, acc[mt][nt], 0, 0, 0);
#pragma unroll
      for (int nt = 0; nt < 4; nt++)
        acc[mt][nt] = __builtin_amdgcn_mfma_f32_16x16x32_bf16(
            al.s, bh[nt].s, acc[mt][nt], 0, 0, 0);
    }
  }

  // partial logits part[slice][row][e]; C/D row=fg*4+j, col=fr
  float* dst = part + (size_t)slice * nrows * EE;
#pragma unroll
  for (int mt = 0; mt < 2; mt++)
#pragma unroll
    for (int j = 0; j < 4; j++) {
      const int r = m0 + 32 * wv + mt * 16 + fg * 4 + j;
#pragma unroll
      for (int nt = 0; nt < 4; nt++)
        dst[(size_t)r * EE + nt * 16 + fr] = acc[mt][nt][j];
    }
}

// ---------------------------------------------------------------------------
// Kernel 2: reduce partials, sqrt(softplus), top-8 (lax.top_k tie-break),
// renormalize, scatter. Flags rows with margin < TAU for exact recompute.
// ---------------------------------------------------------------------------
__global__ __launch_bounds__(256) void topk_kernel(
    const float* __restrict__ part, const float* __restrict__ bias,
    float* __restrict__ out, int nrows, int ksplit, int* __restrict__ counter,
    int* __restrict__ list) {
  const int lane = threadIdx.x & 63;
  const int row = blockIdx.x * 4 + (threadIdx.x >> 6);

  float logit = 0.0f;
  for (int s = 0; s < ksplit; s++)
    logit += part[(size_t)s * nrows * EE + (size_t)row * EE + lane];

  float sp = (logit > 0.0f) ? (logit + log1pf(expf(-logit)))
                            : log1pf(expf(logit));
  float score = sqrtf(sp);
  float sel = score + bias[lane];

  float denom = 0.0f, v8 = 0.0f;
  bool chosen = false;
#pragma unroll
  for (int t = 0; t < 8; t++) {
    float v = sel;
    int idx = lane;
#pragma unroll
    for (int m = 1; m < 64; m <<= 1) {
      float ov = __shfl_xor(v, m, 64);
      int oi = __shfl_xor(idx, m, 64);
      if (ov > v || (ov == v && oi < idx)) { v = ov; idx = oi; }
    }
    float wscore = __shfl(score, idx, 64);
    denom += wscore;
    v8 = v;
    if (lane == idx) { chosen = true; sel = NEG_SENTINEL; }
  }
  float v9 = sel;
#pragma unroll
  for (int m = 1; m < 64; m <<= 1) v9 = fmaxf(v9, __shfl_xor(v9, m, 64));
  if (lane == 0 && (v8 - v9) < TAU) {
    int ix = atomicAdd(counter, 1);
    if (ix < MAXFIX) list[ix] = row;
  }

  denom = fmaxf(denom, 1e-12f);
  out[(size_t)row * EE + lane] = chosen ? (score / denom) : 0.0f;
  out[(size_t)nrows * EE + (size_t)row * EE + lane] = chosen ? 1.0f : 0.0f;
}

// ---------------------------------------------------------------------------
// Kernel 3a: exact-f32 partial dots for flagged rows, k-split 16 ways.
// ---------------------------------------------------------------------------
__global__ __launch_bounds__(256) void fixup_partial(
    const float* __restrict__ hidden, const float* __restrict__ gate_w,
    const int* __restrict__ counter, const int* __restrict__ list,
    float* __restrict__ part2) {
  __shared__ float red[EE][4];
  int cnt = *counter;
  if (cnt > MAXFIX) cnt = MAXFIX;
  const int total = cnt * 16;
  const int e = threadIdx.x & 63;
  const int q = threadIdx.x >> 6;
  for (int w = blockIdx.x; w < total; w += gridDim.x) {
    const int i = w >> 4;
    const int c = w & 15;
    const int row = list[i];
    const int kb = c * 256 + q * 64;
    const float* hp = hidden + (size_t)row * DD + kb;
    const float* wp = gate_w + (size_t)e * DD + kb;
    float s = 0.f;
#pragma unroll
    for (int k = 0; k < 64; k += 4) {
      float4 aa = *(const float4*)(hp + k);
      float4 bb = *(const float4*)(wp + k);
      s = fmaf(aa.w, bb.w, fmaf(aa.z, bb.z, fmaf(aa.y, bb.y, fmaf(aa.x, bb.x, s))));
    }
    red[e][q] = s;
    __syncthreads();
    if (threadIdx.x < EE)
      part2[(size_t)i * 1024 + threadIdx.x * 16 + c] =
          (red[threadIdx.x][0] + red[threadIdx.x][1]) +
          (red[threadIdx.x][2] + red[threadIdx.x][3]);
    __syncthreads();
  }
}

// ---------------------------------------------------------------------------
// Kernel 3b: sum the 16 chunks in fixed order, redo top-8 exactly, rewrite.
// ---------------------------------------------------------------------------
__global__ __launch_bounds__(256) void fixup_apply(
    const float* __restrict__ part2, const float* __restrict__ bias,
    const int* __restrict__ counter, const int* __restrict__ list,
    float* __restrict__ out, int nrows) {
  int cnt = *counter;
  if (cnt > MAXFIX) cnt = MAXFIX;
  const int lane = threadIdx.x & 63;
  const int wv = threadIdx.x >> 6;
  for (int i0 = blockIdx.x * 4; i0 < cnt; i0 += gridDim.x * 4) {
    const int i = i0 + wv;
    if (i >= cnt) continue;
    const int row = list[i];
    const float* pp = part2 + (size_t)i * 1024 + lane * 16;
    float logit = 0.f;
#pragma unroll
    for (int c = 0; c < 16; c++) logit += pp[c];
    float sp = (logit > 0.0f) ? (logit + log1pf(expf(-logit)))
                              : log1pf(expf(logit));
    float score = sqrtf(sp);
    float sel = score + bias[lane];
    float denom = 0.0f;
    bool chosen = false;
#pragma unroll
    for (int k = 0; k < 8; k++) {
      float v = sel;
      int idx = lane;
#pragma unroll
      for (int m = 1; m < 64; m <<= 1) {
        float ov = __shfl_xor(v, m, 64);
        int oi = __shfl_xor(idx, m, 64);
        if (ov > v || (ov == v && oi < idx)) { v = ov; idx = oi; }
      }
      float wscore = __shfl(score, idx, 64);
      denom += wscore;
      if (lane == idx) { chosen = true; sel = NEG_SENTINEL; }
    }
    denom = fmaxf(denom, 1e-12f);
    out[(size_t)row * EE + lane] = chosen ? (score / denom) : 0.0f;
    out[(size_t)nrows * EE + (size_t)row * EE + lane] = chosen ? 1.0f : 0.0f;
  }
}

// ---------------------------------------------------------------------------
extern "C" void kernel_launch(void* const* d_in, const int* in_sizes, int n_in,
                              void* d_out, int out_size, void* d_ws,
                              size_t ws_size, hipStream_t stream) {
  const float* hidden = (const float*)d_in[0];
  const float* gate_w = (const float*)d_in[1];
  const float* bias = (const float*)d_in[2];
  float* out = (float*)d_out;
  char* ws = (char*)d_ws;

  const int nrows = in_sizes[0] / DD;  // 16384

  // ws: bglob @0 (1MB) | part @2MB (32MB) | part2 @36MB (16MB) | tail ctr
  char* bglob = ws;
  float* part = (float*)(ws + (size_t)2 * 1024 * 1024);
  float* part2 = (float*)(ws + (size_t)36 * 1024 * 1024);
  size_t tail = (ws_size - 65536) & ~(size_t)255;
  int* counter = (int*)(ws + tail);
  int* list = counter + 1;

  hipMemsetAsync(counter, 0, sizeof(int), stream);
  presplit_b<<<dim3(128), dim3(256), 0, stream>>>(gate_w, bglob);
  gemm_mfma<<<dim3(nrows / 128, 8), dim3(256), 0, stream>>>(hidden, bglob,
                                                            part, nrows);
  topk_kernel<<<dim3(nrows / 4), dim3(256), 0, stream>>>(part, bias, out,
                                                         nrows, 8, counter,
                                                         list);
  fixup_partial<<<dim3(2048), dim3(256), 0, stream>>>(hidden, gate_w, counter,
                                                      list, part2);
  fixup_apply<<<dim3(512), dim3(256), 0, stream>>>(part2, bias, counter, list,
                                                   out, nrows);
}

// Round 18
// 110.653 us; speedup vs baseline: 1.4960x; 1.0214x over previous
//
#include <hip/hip_runtime.h>
#include <math.h>

#define DD 4096
#define EE 64
#define TAU 1e-4f
#define NEG_SENTINEL -1.0e30f
#define MAXFIX 4096

typedef __attribute__((ext_vector_type(8))) short short8v;
typedef __attribute__((ext_vector_type(4))) float f32x4;

union BF8 { uint4 u; short8v s; };

__device__ __forceinline__ unsigned asu(float f) {
  union { float f; unsigned u; } v; v.f = f; return v.u;
}
__device__ __forceinline__ float asf(unsigned u) {
  union { unsigned u; float f; } v; v.u = u; return v.f;
}
__device__ __forceinline__ unsigned rne_hi(float x) {  // bf16 bits<<16
  unsigned u = asu(x);
  return (u + 0x7fffu + ((u >> 16) & 1u)) & 0xffff0000u;
}
// Split 8 f32 into hi/lo bf16 (RNE both): x = hi + lo + O(2^-17 |x|).
__device__ __forceinline__ void split8(const float x[8], uint4& hi, uint4& lo) {
  unsigned h[8], l[8];
#pragma unroll
  for (int j = 0; j < 8; j++) {
    h[j] = rne_hi(x[j]);
    l[j] = rne_hi(x[j] - asf(h[j]));
  }
  hi = make_uint4((h[0] >> 16) | h[1], (h[2] >> 16) | h[3],
                  (h[4] >> 16) | h[5], (h[6] >> 16) | h[7]);
  lo = make_uint4((l[0] >> 16) | l[1], (l[2] >> 16) | l[3],
                  (l[4] >> 16) | l[5], (l[6] >> 16) | l[7]);
}
// global -> LDS direct copy, 16B/lane; LDS dest wave-uniform (HW adds l*16).
__device__ __forceinline__ void gload16(const void* g, void* l) {
  __builtin_amdgcn_global_load_lds(
      (const __attribute__((address_space(1))) uint32_t*)(uintptr_t)g,
      (__attribute__((address_space(3))) uint32_t*)(uint32_t)(uintptr_t)l, 16,
      0, 0);
}

// ---------------------------------------------------------------------------
// Kernel 0: pre-split gate_w into bf16 hi/lo in the gemm's exact STAGED
// layout (R14-identical): bglob[slice(512k)][step(32k)][hi|lo][e][slot16B];
// source k-octet o of expert e -> slot (o&3) ^ ((e>>1)&3). Also zeroes the
// fixup counter (folds the former hipMemsetAsync dispatch).
// ---------------------------------------------------------------------------
__global__ __launch_bounds__(256) void presplit_b(const float* __restrict__ gw,
                                                  char* __restrict__ bglob,
                                                  int* __restrict__ counter) {
  if (blockIdx.x == 0 && threadIdx.x == 0) *counter = 0;
  const int t = blockIdx.x * 256 + threadIdx.x;  // 64 e x 512 octets
  const int e = t >> 9;
  const int o = t & 511;
  const int slice = o >> 6;   // 64 octets per 512-k slice
  const int ow = o & 63;
  const int step = ow >> 2;   // 4 octets per 32-k step
  const int oslot = ow & 3;
  const float* src = gw + e * DD + o * 8;
  float4 v0 = *(const float4*)src;
  float4 v1 = *(const float4*)(src + 4);
  float x[8] = {v0.x, v0.y, v0.z, v0.w, v1.x, v1.y, v1.z, v1.w};
  uint4 hi, lo;
  split8(x, hi, lo);
  char* dst = bglob + (size_t)slice * 131072 + step * 8192 + e * 64 +
              ((oslot ^ ((e >> 1) & 3)) << 4);
  *(uint4*)dst = hi;
  *(uint4*)(dst + 4096) = lo;
}

// ---------------------------------------------------------------------------
// Kernel 1 (R18 = R14, best measured): staged bf16-split MFMA partial GEMM.
// Block = 256 rows x 64 e; 4 waves; wave = 64 rows (mt=4) x 64 e (nt=4).
// ksplit=8 -> grid (64,8) = 512 = 2 blocks/CU.
// Per 32-k step per block: A 32KB (f32, source-swizzled gload_lds) + B 8KB
// (pre-split bf16, staged verbatim). LDS ring 2 x {A 32K, B 8K} = 80KB.
// stage(t+1) -> compute(t) -> __syncthreads. (R13 deep-ring and R17
// two-barrier variants measured tied-or-worse; this is the banked best.)
// ---------------------------------------------------------------------------
__global__ __launch_bounds__(256, 2) void gemm_mfma(
    const float* __restrict__ hidden, const char* __restrict__ bglob,
    float* __restrict__ part, int nrows) {
  __shared__ __align__(16) char smem[81920];  // 2 bufs x [A 32K | B 8K]

  const int lane = threadIdx.x & 63;
  const int wv = threadIdx.x >> 6;
  const int fr = lane & 15;
  const int fg = lane >> 4;  // 0..3
  const int m0 = blockIdx.x * 256;
  const int slice = blockIdx.y;  // ksplit = 8, kslice = 512
  const int k0 = slice * 512;

  const float* srcA[8];
#pragma unroll
  for (int i = 0; i < 8; i++) {
    const int rloc = 8 * i + (lane >> 3);
    const int s = (lane & 7) ^ (rloc & 7);
    srcA[i] = hidden + (size_t)(m0 + 64 * wv + rloc) * DD + k0 + s * 4;
  }
  const char* srcB = bglob + (size_t)slice * 131072 + wv * 2048 + lane * 16;

  auto stage = [&](int t) {
    const int buf = t & 1;
    char* ad = smem + buf * 40960 + wv * 8192;
    char* bd = smem + buf * 40960 + 32768 + wv * 2048;
#pragma unroll
    for (int i = 0; i < 8; i++) gload16(srcA[i] + t * 32, ad + i * 1024);
#pragma unroll
    for (int i = 0; i < 2; i++)
      gload16(srcB + t * 8192 + i * 1024, bd + i * 1024);
  };

  f32x4 zero4 = {0.f, 0.f, 0.f, 0.f};
  f32x4 acc[4][4];
#pragma unroll
  for (int mt = 0; mt < 4; mt++)
#pragma unroll
    for (int nt = 0; nt < 4; nt++) acc[mt][nt] = zero4;

  const int bslot = (fg ^ ((fr >> 1) & 3)) << 4;

  stage(0);
  __syncthreads();

  for (int t = 0; t < 16; t++) {
    if (t + 1 < 16) stage(t + 1);
    const char* Ab = smem + (t & 1) * 40960 + wv * 8192;
    const char* Bb = smem + (t & 1) * 40960 + 32768;
    BF8 bh[4], bl[4];
#pragma unroll
    for (int nt = 0; nt < 4; nt++) {
      const int boff = (nt * 16 + fr) * 64 + bslot;
      bh[nt].u = *(const uint4*)(Bb + boff);
      bl[nt].u = *(const uint4*)(Bb + 4096 + boff);
    }
#pragma unroll
    for (int mt = 0; mt < 4; mt++) {
      const int arow = (mt * 16 + fr) * 128;
      float4 a0 = *(const float4*)(Ab + arow + (((2 * fg + 0) ^ (fr & 7)) << 4));
      float4 a1 = *(const float4*)(Ab + arow + (((2 * fg + 1) ^ (fr & 7)) << 4));
      float xa[8] = {a0.x, a0.y, a0.z, a0.w, a1.x, a1.y, a1.z, a1.w};
      BF8 ah, al;
      split8(xa, ah.u, al.u);
      // per-acc order hh -> hl -> lh (deterministic)
#pragma unroll
      for (int nt = 0; nt < 4; nt++)
        acc[mt][nt] = __builtin_amdgcn_mfma_f32_16x16x32_bf16(
            ah.s, bh[nt].s, acc[mt][nt], 0, 0, 0);
#pragma unroll
      for (int nt = 0; nt < 4; nt++)
        acc[mt][nt] = __builtin_amdgcn_mfma_f32_16x16x32_bf16(
            ah.s, bl[nt].s, acc[mt][nt], 0, 0, 0);
#pragma unroll
      for (int nt = 0; nt < 4; nt++)
        acc[mt][nt] = __builtin_amdgcn_mfma_f32_16x16x32_bf16(
            al.s, bh[nt].s, acc[mt][nt], 0, 0, 0);
    }
    __syncthreads();
  }

  // partial logits part[slice][row][e]; C/D row=fg*4+j, col=fr
  float* dst = part + (size_t)slice * nrows * EE;
#pragma unroll
  for (int mt = 0; mt < 4; mt++)
#pragma unroll
    for (int j = 0; j < 4; j++) {
      const int r = m0 + 64 * wv + mt * 16 + fg * 4 + j;
#pragma unroll
      for (int nt = 0; nt < 4; nt++)
        dst[(size_t)r * EE + nt * 16 + fr] = acc[mt][nt][j];
    }
}

// ---------------------------------------------------------------------------
// Kernel 2: reduce partials, sqrt(softplus), top-8 (lax.top_k tie-break),
// renormalize, scatter. Flags rows with margin < TAU for exact recompute.
// ---------------------------------------------------------------------------
__global__ __launch_bounds__(256) void topk_kernel(
    const float* __restrict__ part, const float* __restrict__ bias,
    float* __restrict__ out, int nrows, int ksplit, int* __restrict__ counter,
    int* __restrict__ list) {
  const int lane = threadIdx.x & 63;
  const int row = blockIdx.x * 4 + (threadIdx.x >> 6);

  float logit = 0.0f;
  for (int s = 0; s < ksplit; s++)
    logit += part[(size_t)s * nrows * EE + (size_t)row * EE + lane];

  float sp = (logit > 0.0f) ? (logit + log1pf(expf(-logit)))
                            : log1pf(expf(logit));
  float score = sqrtf(sp);
  float sel = score + bias[lane];

  float denom = 0.0f, v8 = 0.0f;
  bool chosen = false;
#pragma unroll
  for (int t = 0; t < 8; t++) {
    float v = sel;
    int idx = lane;
#pragma unroll
    for (int m = 1; m < 64; m <<= 1) {
      float ov = __shfl_xor(v, m, 64);
      int oi = __shfl_xor(idx, m, 64);
      if (ov > v || (ov == v && oi < idx)) { v = ov; idx = oi; }
    }
    float wscore = __shfl(score, idx, 64);
    denom += wscore;
    v8 = v;
    if (lane == idx) { chosen = true; sel = NEG_SENTINEL; }
  }
  float v9 = sel;
#pragma unroll
  for (int m = 1; m < 64; m <<= 1) v9 = fmaxf(v9, __shfl_xor(v9, m, 64));
  if (lane == 0 && (v8 - v9) < TAU) {
    int ix = atomicAdd(counter, 1);
    if (ix < MAXFIX) list[ix] = row;
  }

  denom = fmaxf(denom, 1e-12f);
  out[(size_t)row * EE + lane] = chosen ? (score / denom) : 0.0f;
  out[(size_t)nrows * EE + (size_t)row * EE + lane] = chosen ? 1.0f : 0.0f;
}

// ---------------------------------------------------------------------------
// Kernel 3a: exact-f32 partial dots for flagged rows, k-split 16 ways.
// ---------------------------------------------------------------------------
__global__ __launch_bounds__(256) void fixup_partial(
    const float* __restrict__ hidden, const float* __restrict__ gate_w,
    const int* __restrict__ counter, const int* __restrict__ list,
    float* __restrict__ part2) {
  __shared__ float red[EE][4];
  int cnt = *counter;
  if (cnt > MAXFIX) cnt = MAXFIX;
  const int total = cnt * 16;
  const int e = threadIdx.x & 63;
  const int q = threadIdx.x >> 6;
  for (int w = blockIdx.x; w < total; w += gridDim.x) {
    const int i = w >> 4;
    const int c = w & 15;
    const int row = list[i];
    const int kb = c * 256 + q * 64;
    const float* hp = hidden + (size_t)row * DD + kb;
    const float* wp = gate_w + (size_t)e * DD + kb;
    float s = 0.f;
#pragma unroll
    for (int k = 0; k < 64; k += 4) {
      float4 aa = *(const float4*)(hp + k);
      float4 bb = *(const float4*)(wp + k);
      s = fmaf(aa.w, bb.w, fmaf(aa.z, bb.z, fmaf(aa.y, bb.y, fmaf(aa.x, bb.x, s))));
    }
    red[e][q] = s;
    __syncthreads();
    if (threadIdx.x < EE)
      part2[(size_t)i * 1024 + threadIdx.x * 16 + c] =
          (red[threadIdx.x][0] + red[threadIdx.x][1]) +
          (red[threadIdx.x][2] + red[threadIdx.x][3]);
    __syncthreads();
  }
}

// ---------------------------------------------------------------------------
// Kernel 3b: sum the 16 chunks in fixed order, redo top-8 exactly, rewrite.
// ---------------------------------------------------------------------------
__global__ __launch_bounds__(256) void fixup_apply(
    const float* __restrict__ part2, const float* __restrict__ bias,
    const int* __restrict__ counter, const int* __restrict__ list,
    float* __restrict__ out, int nrows) {
  int cnt = *counter;
  if (cnt > MAXFIX) cnt = MAXFIX;
  const int lane = threadIdx.x & 63;
  const int wv = threadIdx.x >> 6;
  for (int i0 = blockIdx.x * 4; i0 < cnt; i0 += gridDim.x * 4) {
    const int i = i0 + wv;
    if (i >= cnt) continue;
    const int row = list[i];
    const float* pp = part2 + (size_t)i * 1024 + lane * 16;
    float logit = 0.f;
#pragma unroll
    for (int c = 0; c < 16; c++) logit += pp[c];
    float sp = (logit > 0.0f) ? (logit + log1pf(expf(-logit)))
                              : log1pf(expf(logit));
    float score = sqrtf(sp);
    float sel = score + bias[lane];
    float denom = 0.0f;
    bool chosen = false;
#pragma unroll
    for (int k = 0; k < 8; k++) {
      float v = sel;
      int idx = lane;
#pragma unroll
      for (int m = 1; m < 64; m <<= 1) {
        float ov = __shfl_xor(v, m, 64);
        int oi = __shfl_xor(idx, m, 64);
        if (ov > v || (ov == v && oi < idx)) { v = ov; idx = oi; }
      }
      float wscore = __shfl(score, idx, 64);
      denom += wscore;
      if (lane == idx) { chosen = true; sel = NEG_SENTINEL; }
    }
    denom = fmaxf(denom, 1e-12f);
    out[(size_t)row * EE + lane] = chosen ? (score / denom) : 0.0f;
    out[(size_t)nrows * EE + (size_t)row * EE + lane] = chosen ? 1.0f : 0.0f;
  }
}

// ---------------------------------------------------------------------------
extern "C" void kernel_launch(void* const* d_in, const int* in_sizes, int n_in,
                              void* d_out, int out_size, void* d_ws,
                              size_t ws_size, hipStream_t stream) {
  const float* hidden = (const float*)d_in[0];
  const float* gate_w = (const float*)d_in[1];
  const float* bias = (const float*)d_in[2];
  float* out = (float*)d_out;
  char* ws = (char*)d_ws;

  const int nrows = in_sizes[0] / DD;  // 16384

  // ws: bglob @0 (1MB) | part @2MB (32MB) | part2 @36MB (16MB) | tail ctr
  char* bglob = ws;
  float* part = (float*)(ws + (size_t)2 * 1024 * 1024);
  float* part2 = (float*)(ws + (size_t)36 * 1024 * 1024);
  size_t tail = (ws_size - 65536) & ~(size_t)255;
  int* counter = (int*)(ws + tail);
  int* list = counter + 1;

  presplit_b<<<dim3(128), dim3(256), 0, stream>>>(gate_w, bglob, counter);
  gemm_mfma<<<dim3(nrows / 256, 8), dim3(256), 0, stream>>>(hidden, bglob,
                                                            part, nrows);
  topk_kernel<<<dim3(nrows / 4), dim3(256), 0, stream>>>(part, bias, out,
                                                         nrows, 8, counter,
                                                         list);
  fixup_partial<<<dim3(2048), dim3(256), 0, stream>>>(hidden, gate_w, counter,
                                                      list, part2);
  fixup_apply<<<dim3(256), dim3(256), 0, stream>>>(part2, bias, counter, list,
                                                   out, nrows);
}